// Round 5
// baseline (204.507 us; speedup 1.0000x reference)
//
#include <hip/hip_runtime.h>
#include <stdint.h>

typedef __bf16 bf16;
typedef __attribute__((ext_vector_type(2))) __bf16 bf16x2;
typedef __attribute__((ext_vector_type(4))) __bf16 bf16x4;
typedef __attribute__((ext_vector_type(8))) __bf16 bf16x8;
typedef __attribute__((ext_vector_type(4))) float f32x4;
typedef __attribute__((ext_vector_type(4))) short s16x4;

#define B_  2
#define S_  2048
#define H_  1024
#define NH_ 16
#define HD_ 64

// async 16B global->LDS. LDS dest = wave-uniform base + lane*16.
__device__ __forceinline__ void glds16(const bf16* g, bf16* l) {
  __builtin_amdgcn_global_load_lds(
      (const __attribute__((address_space(1))) uint32_t*)g,
      (__attribute__((address_space(3))) uint32_t*)l, 16, 0, 0);
}

// PV MFMA: 16x16x16 bf16 — B operand layout (k=quad*4+e, col=l15) matches the
// S^T MFMA D layout exactly, so softmax P registers feed it with NO relayout.
__device__ __forceinline__ f32x4 pv_mfma(bf16x4 a, bf16x4 b, f32x4 c) {
#if __has_builtin(__builtin_amdgcn_mfma_f32_16x16x16bf16_1k)
  union U { bf16x4 h; s16x4 s; };
  U ua; ua.h = a;
  U ub; ub.h = b;
  return __builtin_amdgcn_mfma_f32_16x16x16bf16_1k(ua.s, ub.s, c, 0, 0, 0);
#else
  f32x4 d;
  asm volatile("v_mfma_f32_16x16x16_bf16 %0, %1, %2, %3\n\ts_nop 7\n\ts_nop 7"
               : "=v"(d) : "v"(a), "v"(b), "v"(c));
  return d;
#endif
}

// ---------------------------------------------------------------------------
// fp32 -> bf16 conversion: y=0 hidden_states, y=1..4 weight matrices.
// ---------------------------------------------------------------------------
__global__ __launch_bounds__(256) void cvt_f32_bf16(
    const float* __restrict__ s0, bf16* __restrict__ d0, int n0,
    const float* __restrict__ s1, bf16* __restrict__ d1,
    const float* __restrict__ s2, bf16* __restrict__ d2,
    const float* __restrict__ s3, bf16* __restrict__ d3,
    const float* __restrict__ s4, bf16* __restrict__ d4, int nw)
{
  const float* s; bf16* d; int n;
  switch (blockIdx.y) {
    case 0:  s = s0; d = d0; n = n0; break;
    case 1:  s = s1; d = d1; n = nw; break;
    case 2:  s = s2; d = d2; n = nw; break;
    case 3:  s = s3; d = d3; n = nw; break;
    default: s = s4; d = d4; n = nw; break;
  }
  const int i = (blockIdx.x * 256 + threadIdx.x) * 8;
  if (i >= n) return;
  float4 v0 = *(const float4*)(s + i);
  float4 v1 = *(const float4*)(s + i + 4);
  bf16x8 o;
  o[0] = (bf16)v0.x; o[1] = (bf16)v0.y; o[2] = (bf16)v0.z; o[3] = (bf16)v0.w;
  o[4] = (bf16)v1.x; o[5] = (bf16)v1.y; o[6] = (bf16)v1.z; o[7] = (bf16)v1.w;
  *(bf16x8*)(d + i) = o;
}

// ---------------------------------------------------------------------------
// Fused QKV GEMM, 8-phase 256x256xBK64 schedule. Writes SEPARATE dense
// Q/K/V [4096][1024] outputs (segment per 256-col tile) so attn reads dense.
// ---------------------------------------------------------------------------
__global__ __launch_bounds__(512, 2) void gemm_qkv_8ph(
    const bf16* __restrict__ X,      // [4096][1024]
    const bf16* __restrict__ Wc,     // [3072][1024] = [Wq;Wk;Wv]
    const float* __restrict__ bq, const float* __restrict__ bk,
    const float* __restrict__ bv,
    bf16* __restrict__ Yq, bf16* __restrict__ Yk, bf16* __restrict__ Yv,
    float qscl)
{
  constexpr int K  = 1024;
  constexpr int NT = K / 64;         // 16 K-tiles

  __shared__ __align__(16) bf16 As[2][256 * 64];
  __shared__ __align__(16) bf16 Bs[2][256 * 64];

  // bijective XCD swizzle (192 = 8 * 24)
  const int f   = blockIdx.x;
  const int swz = (f & 7) * 24 + (f >> 3);
  const int by  = swz / 12, bx = swz % 12;
  const int m0  = by * 256, n0 = bx * 256;

  const int tid  = threadIdx.x;
  const int lane = tid & 63;
  const int wave = tid >> 6;
  const int quad = lane >> 4;
  const int l15  = lane & 15;
  const int wm   = (wave >> 2) * 128;
  const int wn   = (wave & 3) * 64;

  const int r0  = tid >> 3;          // staging row within 64-row group
  const int kc0 = tid & 7;           // staging 16B-chunk within row

  const bf16* Xb = X  + (size_t)m0 * K;
  const bf16* Wb = Wc + (size_t)n0 * K;

  f32x4 acc[8][4] = {};

#define SBAR() asm volatile("s_barrier" ::: "memory")
#define VM0()  asm volatile("s_waitcnt vmcnt(0)" ::: "memory")
#define STG(MAT, G, cb_, h)                                                 \
  { _Pragma("unroll") for (int s = 0; s < 2; ++s) {                         \
      const int row = (h) * 128 + s * 64 + r0;                              \
      const int sc  = kc0 ^ (row & 7);                                      \
      glds16((G) + (size_t)row * K + sc * 8,                                \
             &MAT[cb_][((h) * 1024 + s * 512 + wave * 64) * 8]); } }
#define RA(mi, ks) (*(const bf16x8*)&As[cb][(wm + (mi) * 16 + l15) * 64 +   \
                     ((((ks) * 4 + quad)) ^ (l15 & 7)) * 8])
#define RB(ni, ks) (*(const bf16x8*)&Bs[cb][(wn + (ni) * 16 + l15) * 64 +   \
                     ((((ks) * 4 + quad)) ^ (l15 & 7)) * 8])
#define MFMA(d, x, y) d = __builtin_amdgcn_mfma_f32_16x16x32_bf16(x, y, d, 0, 0, 0)

  // prologue: tile 0 into buf 0
  STG(As, Xb, 0, 0); STG(As, Xb, 0, 1);
  STG(Bs, Wb, 0, 0); STG(Bs, Wb, 0, 1);
  VM0();
  SBAR();

  for (int t = 0; t < NT; ++t) {
    const int cb = t & 1, sb = cb ^ 1;
    const bf16* Xn = Xb + (t + 1) * 64;
    const bf16* Wn = Wb + (t + 1) * 64;
    const bool pre = (t + 1 < NT);

    bf16x8 a[4][2], b[4][2];

    // ---- P1: read A-lo (8) + B-lo (4); stage A(t+1) ----
#pragma unroll
    for (int mi = 0; mi < 4; ++mi) { a[mi][0] = RA(mi, 0); a[mi][1] = RA(mi, 1); }
#pragma unroll
    for (int ni = 0; ni < 2; ++ni) { b[ni][0] = RB(ni, 0); b[ni][1] = RB(ni, 1); }
    if (pre) { STG(As, Xn, sb, 0); STG(As, Xn, sb, 1); }
    SBAR();
    __builtin_amdgcn_s_setprio(1);
#pragma unroll
    for (int mi = 0; mi < 4; ++mi)
#pragma unroll
      for (int ni = 0; ni < 2; ++ni) {
        MFMA(acc[mi][ni], a[mi][0], b[ni][0]);
        MFMA(acc[mi][ni], a[mi][1], b[ni][1]);
      }
    __builtin_amdgcn_s_setprio(0);
    SBAR();

    // ---- P2: read B-hi (4); stage B(t+1) ----
#pragma unroll
    for (int ni = 2; ni < 4; ++ni) { b[ni][0] = RB(ni, 0); b[ni][1] = RB(ni, 1); }
    if (pre) { STG(Bs, Wn, sb, 0); STG(Bs, Wn, sb, 1); }
    SBAR();
    __builtin_amdgcn_s_setprio(1);
#pragma unroll
    for (int mi = 0; mi < 4; ++mi)
#pragma unroll
      for (int ni = 2; ni < 4; ++ni) {
        MFMA(acc[mi][ni], a[mi][0], b[ni][0]);
        MFMA(acc[mi][ni], a[mi][1], b[ni][1]);
      }
    __builtin_amdgcn_s_setprio(0);
    SBAR();

    // ---- P3: read A-hi (8) ----
#pragma unroll
    for (int mi = 0; mi < 4; ++mi) { a[mi][0] = RA(mi + 4, 0); a[mi][1] = RA(mi + 4, 1); }
    SBAR();
    __builtin_amdgcn_s_setprio(1);
#pragma unroll
    for (int mi = 0; mi < 4; ++mi)
#pragma unroll
      for (int ni = 0; ni < 2; ++ni) {
        MFMA(acc[mi + 4][ni], a[mi][0], b[ni][0]);
        MFMA(acc[mi + 4][ni], a[mi][1], b[ni][1]);
      }
    __builtin_amdgcn_s_setprio(0);
    SBAR();

    // ---- P4: register-only MFMA; once-per-tile counted drain ----
    __builtin_amdgcn_s_setprio(1);
#pragma unroll
    for (int mi = 0; mi < 4; ++mi)
#pragma unroll
      for (int ni = 2; ni < 4; ++ni) {
        MFMA(acc[mi + 4][ni], a[mi][0], b[ni][0]);
        MFMA(acc[mi + 4][ni], a[mi][1], b[ni][1]);
      }
    __builtin_amdgcn_s_setprio(0);
    VM0();
    SBAR();       // publishes buf sb for tile t+1
  }

  // epilogue: bias + per-segment scale, separate dense outputs
  const int seg = bx >> 2;
  const float* bias = seg == 0 ? bq : (seg == 1 ? bk : bv);
  bf16* Yp = seg == 0 ? Yq : (seg == 1 ? Yk : Yv);
  const float ysc = seg == 0 ? qscl : 1.0f;
  const int nc0 = n0 - seg * 1024;
#pragma unroll
  for (int mi = 0; mi < 8; ++mi) {
    const int row = m0 + wm + mi * 16 + quad * 4;
#pragma unroll
    for (int ni = 0; ni < 4; ++ni) {
      const int col = nc0 + wn + ni * 16 + l15;
      const float bvv = bias[col];
#pragma unroll
      for (int r = 0; r < 4; ++r)
        Yp[(size_t)(row + r) * H_ + col] = (bf16)((acc[mi][ni][r] + bvv) * ysc);
    }
  }
#undef SBAR
#undef VM0
#undef STG
#undef RA
#undef RB
#undef MFMA
}

// ---------------------------------------------------------------------------
// GEMM: Y[m,n] = (sum_k X[m,k]*W[n,k] + bias[n]) (O-projection).
// 128x128 tile, BK=32. Double-buffered LDS + glds16, ONE barrier per iter.
// ---------------------------------------------------------------------------
template <typename TY>
__global__ __launch_bounds__(256) void gemm_bt_bias(
    const bf16* __restrict__ X, const bf16* __restrict__ W,
    const float* __restrict__ bias, TY* __restrict__ Y,
    int M, int N, int K)
{
  __shared__ __align__(16) bf16 As[2][128 * 32];
  __shared__ __align__(16) bf16 Bs[2][128 * 32];

  const int tid  = threadIdx.x;
  const int lane = tid & 63;
  const int wave = tid >> 6;
  const int m0 = blockIdx.y * 128;
  const int n0 = blockIdx.x * 128;
  const int wm = (wave >> 1) * 64;
  const int wn = (wave & 1) * 64;

  const int r0 = tid >> 2,            c0 = (tid & 3) * 8;
  const int r1 = (256 + tid) >> 2,    c1 = ((256 + tid) & 3) * 8;
  const int cb0 = (wave * 64) * 8;
  const int cb1 = (256 + wave * 64) * 8;

  f32x4 acc[4][4] = {};

  glds16(X + (size_t)(m0 + r0) * K + c0, &As[0][cb0]);
  glds16(W + (size_t)(n0 + r0) * K + c0, &Bs[0][cb0]);
  glds16(X + (size_t)(m0 + r1) * K + c1, &As[0][cb1]);
  glds16(W + (size_t)(n0 + r1) * K + c1, &Bs[0][cb1]);

  int pb = 0;
  for (int k0 = 0; k0 < K; k0 += 32, pb ^= 1) {
    __syncthreads();

    if (k0 + 32 < K) {
      const int kn = k0 + 32;
      glds16(X + (size_t)(m0 + r0) * K + kn + c0, &As[pb ^ 1][cb0]);
      glds16(W + (size_t)(n0 + r0) * K + kn + c0, &Bs[pb ^ 1][cb0]);
      glds16(X + (size_t)(m0 + r1) * K + kn + c1, &As[pb ^ 1][cb1]);
      glds16(W + (size_t)(n0 + r1) * K + kn + c1, &Bs[pb ^ 1][cb1]);
    }

    bf16x8 a[4], b[4];
#pragma unroll
    for (int i = 0; i < 4; ++i)
      a[i] = *(const bf16x8*)&As[pb][(wm + i * 16 + (lane & 15)) * 32 + (lane >> 4) * 8];
#pragma unroll
    for (int i = 0; i < 4; ++i)
      b[i] = *(const bf16x8*)&Bs[pb][(wn + i * 16 + (lane & 15)) * 32 + (lane >> 4) * 8];
#pragma unroll
    for (int mi = 0; mi < 4; ++mi)
#pragma unroll
      for (int ni = 0; ni < 4; ++ni)
        acc[mi][ni] = __builtin_amdgcn_mfma_f32_16x16x32_bf16(a[mi], b[ni], acc[mi][ni], 0, 0, 0);
  }

#pragma unroll
  for (int mi = 0; mi < 4; ++mi) {
    const int row = m0 + wm + mi * 16 + (lane >> 4) * 4;
#pragma unroll
    for (int ni = 0; ni < 4; ++ni) {
      const int col = n0 + wn + ni * 16 + (lane & 15);
      const float bv = bias[col];
#pragma unroll
      for (int r = 0; r < 4; ++r)
        Y[(size_t)(row + r) * N + col] = (TY)(acc[mi][ni][r] + bv);
    }
  }
}

// ---------------------------------------------------------------------------
// Flash attention, causal. R5: ROLE-SPLIT 8-wave blocks (512 thr): waves 0-3
// own q-tile (31-p), waves 4-7 own q-tile p — ONE tile-step per wave per
// iter (serial chain halved) and 16 waves/CU (4/SIMD TLP, was 2).  Same
// merged k-loop / double-buffer / one barrier per iter.  Vt swizzle redone
// bijectively: pos = c ^ ((row&7)<<2) ^ ((row>>3)&1) ^ ((row>>4)<<1) on
// BOTH write and read -> conflict-free PV b64 reads (old quad^l15 pattern
// collapsed to 8 values = measured 4.45M conflict cycles).
// ---------------------------------------------------------------------------
__device__ __forceinline__ void attn_tile_step(
    const bf16* Ksb, const bf16* Vtb, const bf16x8 bq[2], int qrow, int k0,
    bool maskit, float& mr, float& lr, f32x4 oacc[4], int l15, int quad)
{
  // ---- S^T = K Q^T ----  (Q pre-scaled by 0.125*log2e in the QKV GEMM)
  f32x4 sacc[8] = {};
  __builtin_amdgcn_s_setprio(1);
#pragma unroll
  for (int ks = 0; ks < 2; ++ks) {
#pragma unroll
    for (int mb = 0; mb < 8; ++mb) {
      const int row = mb * 16 + l15;
      const int ch  = (ks * 4 + quad) ^ (l15 & 7);   // XOR de-swizzle
      bf16x8 ak = *(const bf16x8*)&Ksb[row * 64 + ch * 8];
      sacc[mb] = __builtin_amdgcn_mfma_f32_16x16x32_bf16(ak, bq[ks], sacc[mb], 0, 0, 0);
    }
  }
  __builtin_amdgcn_s_setprio(0);

  // causal mask (only on the final k-tile of this q-tile)
  if (maskit) {
#pragma unroll
    for (int mb = 0; mb < 8; ++mb) {
      const int kb = k0 + mb * 16 + quad * 4;
#pragma unroll
      for (int r = 0; r < 4; ++r)
        if (kb + r > qrow) sacc[mb][r] = -1e30f;
    }
  }

  // max tree + shuffles — runs in PARALLEL with the exp2/PV chain below
  float mx = -1e30f;
#pragma unroll
  for (int mb = 0; mb < 8; ++mb)
    mx = fmaxf(mx, fmaxf(fmaxf(sacc[mb][0], sacc[mb][1]),
                         fmaxf(sacc[mb][2], sacc[mb][3])));
  mx = fmaxf(mx, __shfl_xor(mx, 16, 64));
  mx = fmaxf(mx, __shfl_xor(mx, 32, 64));

  // speculative exp2 with CURRENT mr (no dependence on mx)
  float sum = 0.0f;
  bf16x4 pwv[8];
#pragma unroll
  for (int mb = 0; mb < 8; ++mb) {
    bf16x4 pw;
#pragma unroll
    for (int r = 0; r < 4; ++r) {
      const float p = __builtin_amdgcn_exp2f(sacc[mb][r] - mr);
      sum += p;
      pw[r] = (bf16)p;
    }
    pwv[mb] = pw;
  }
  sum += __shfl_xor(sum, 16, 64);
  sum += __shfl_xor(sum, 32, 64);

  // ---- O^T += V^T P^T : 16x16x16, P direct from registers ----
  __builtin_amdgcn_s_setprio(1);
#pragma unroll
  for (int mb = 0; mb < 8; ++mb) {
#pragma unroll
    for (int db = 0; db < 4; ++db) {
      const int vch = (mb * 4 + quad) ^ ((l15 & 7) << 2) ^ ((l15 >> 3) & 1) ^ (db << 1);
      bf16x4 av = *(const bf16x4*)&Vtb[(db * 16 + l15) * 128 + vch * 4];
      oacc[db] = pv_mfma(av, pwv[mb], oacc[db]);
    }
  }
  __builtin_amdgcn_s_setprio(0);

  lr += sum;
  // rare fixup: rescale AFTER accumulation (exact: O' = a*(O_old + P·V))
  if (!__all(mx <= mr + 8.0f)) {
    const float mnew  = fmaxf(mr, mx);
    const float alpha = __builtin_amdgcn_exp2f(mr - mnew);
    lr *= alpha;
#pragma unroll
    for (int db = 0; db < 4; ++db)
#pragma unroll
      for (int r = 0; r < 4; ++r) oacc[db][r] *= alpha;
    mr = mnew;
  }
}

__global__ __launch_bounds__(512, 4) void attn_causal(
    const bf16* __restrict__ Q, const bf16* __restrict__ K,
    const bf16* __restrict__ V, bf16* __restrict__ O)
{
  // XCD-chunked decode: all 16 pair-blocks of a bh land on one XCD (lin%8).
  // Note blocks lin and lin+256 (co-resident on a CU) share the same pair.
  const int lin  = blockIdx.x;               // 0..511
  const int slot = lin >> 3;                 // 0..63
  const int bh   = (lin & 7) * 4 + (slot >> 4);
  const int pair = slot & 15;
  const int b    = bh >> 4;
  const int h    = bh & 15;

  const int tid  = threadIdx.x;
  const int lane = tid & 63;
  const int wave = tid >> 6;                 // 0..7
  const int quad = lane >> 4;
  const int l15  = lane & 15;
  const size_t headoff = (size_t)b * S_ * H_ + (size_t)h * HD_;
  const bf16* Kp = K + headoff;
  const bf16* Vp = V + headoff;

  __shared__ __align__(16) bf16 Ks[2][128 * 64];    // chunk-XOR swizzled
  __shared__ __align__(16) bf16 Vt[2][64 * 128];    // Vt[d][key], pos-swizzled

  const int qlo = pair, qhi = 31 - pair;
  const int nl  = (qlo >> 1) + 1;      // 1..8
  const int nh  = (qhi >> 1) + 1;      // 9..16
  const bool isH = wave < 4;
  const int  myq = isH ? qhi : qlo;
  const int  myn = isH ? nh  : nl;
  const int qrow = myq * 64 + (wave & 3) * 16 + l15;

  // Q fragments in registers (pre-scaled by QKV GEMM)
  bf16x8 bq[2];
  bq[0] = *(const bf16x8*)(Q + headoff + (size_t)qrow * H_ + quad * 8);
  bq[1] = *(const bf16x8*)(Q + headoff + (size_t)qrow * H_ + 32 + quad * 8);

  // --- staging maps (512 threads) ---
  // K: 1024 16B-chunks, 2 per thread, XOR-pre-swizzled global source.
  // V: key-pair kp = tid&63 -> keys 2kp,2kp+1; col group g = tid>>6 -> 8 cols.
  const int kp = tid & 63;
  const int g  = tid >> 6;

#define STAGE_K(k0_, buf_)                                                  \
  {                                                                         \
    _Pragma("unroll")                                                       \
    for (int i = 0; i < 2; ++i) {                                           \
      const int n = i * 512 + tid;                                          \
      const int row = n >> 3;                                               \
      const int cg  = (n & 7) ^ (row & 7);                                  \
      glds16(Kp + (size_t)((k0_) + row) * H_ + cg * 8,                      \
             &Ks[buf_][(i * 512 + wave * 64) * 8]);                         \
    }                                                                       \
  }

#define LOAD_V(k0_)                                                         \
  {                                                                         \
    vreg[0] = *(const bf16x8*)(Vp + (size_t)((k0_) + 2 * kp) * H_ + g * 8); \
    vreg[1] = *(const bf16x8*)(Vp + (size_t)((k0_) + 2 * kp + 1) * H_ + g * 8);\
  }

// Vt write: pos = (key>>2) ^ ((row&7)<<2) ^ ((row>>3)&1) ^ ((row>>4)<<1);
// adjacent keys 2kp,2kp+1 share pos -> one b32 write per (row,pair).
#define WRITE_V(buf_)                                                       \
  {                                                                         \
    _Pragma("unroll")                                                       \
    for (int e = 0; e < 8; ++e) {                                           \
      const int row = g * 8 + e;                                            \
      const int pos = (kp >> 1) ^ ((row & 7) << 2) ^ ((row >> 3) & 1)       \
                      ^ ((row >> 4) << 1);                                  \
      bf16x2 pw; pw[0] = vreg[0][e]; pw[1] = vreg[1][e];                    \
      *(bf16x2*)&Vt[buf_][row * 128 + pos * 4 + ((2 * kp) & 3)] = pw;       \
    }                                                                       \
  }

  bf16x8 vreg[2];

  // prologue: tile 0 -> buf 0
  STAGE_K(0, 0);
  LOAD_V(0);
  WRITE_V(0);
  __syncthreads();

  float mr = 0.0f, lr = 0.0f;
  f32x4 oacc[4] = {};

  for (int it = 0; it < nh; ++it) {
    const int c = it & 1;
    const bool pre = (it + 1 < nh);

    if (pre) {                       // prefetch tile it+1 into buf c^1
      STAGE_K((it + 1) * 128, c ^ 1);
      LOAD_V((it + 1) * 128);
    }

    if (it < myn)
      attn_tile_step(Ks[c], Vt[c], bq, qrow, it * 128, it == myn - 1,
                     mr, lr, oacc, l15, quad);

    if (pre) {
      WRITE_V(c ^ 1);                // reg->LDS after compute (write-late)
      __syncthreads();               // drains glds + V writes; publishes c^1
    }
  }

  // epilogue
  const float inv = 1.0f / lr;
#pragma unroll
  for (int db = 0; db < 4; ++db) {
    bf16x4 o;
#pragma unroll
    for (int r = 0; r < 4; ++r) o[r] = (bf16)(oacc[db][r] * inv);
    *(bf16x4*)(O + headoff + (size_t)qrow * H_ + db * 16 + quad * 4) = o;
  }
#undef STAGE_K
#undef LOAD_V
#undef WRITE_V
}

extern "C" void kernel_launch(void* const* d_in, const int* in_sizes, int n_in,
                              void* d_out, int out_size, void* d_ws, size_t ws_size,
                              hipStream_t stream) {
  const float* hs = (const float*)d_in[0];
  const float* Wq = (const float*)d_in[1]; const float* bq = (const float*)d_in[2];
  const float* Wk = (const float*)d_in[3]; const float* bk = (const float*)d_in[4];
  const float* Wv = (const float*)d_in[5]; const float* bv = (const float*)d_in[6];
  const float* Wo = (const float*)d_in[7]; const float* bo = (const float*)d_in[8];
  float* out = (float*)d_out;

  const size_t elems = (size_t)B_ * S_ * H_;   // 4,194,304
  const size_t wel   = (size_t)H_ * H_;        // 1,048,576
  // workspace (40 MB): [hsb | AO aliased 8MB][W bf16 8MB][Q 8][K 8][V 8]
  bf16* hsb = (bf16*)d_ws;      // read only by QKV GEMM
  bf16* AO  = hsb;              // written by attn (hsb dead by then)
  bf16* Wqb = hsb + elems;      // Wq;Wk;Wv contiguous = fused Wc
  bf16* Wkb = Wqb + wel;
  bf16* Wvb = Wkb + wel;
  bf16* Wob = Wvb + wel;
  bf16* Qw  = Wob + wel;
  bf16* Kw  = Qw + elems;
  bf16* Vw  = Kw + elems;

  cvt_f32_bf16<<<dim3(2048, 5), dim3(256), 0, stream>>>(
      hs, hsb, (int)elems, Wq, Wqb, Wk, Wkb, Wv, Wvb, Wo, Wob, (int)wel);

  const int M = B_ * S_;   // 4096
  const float QSCL = 0.125f * 1.44269504f;   // (1/sqrt(64)) * log2(e)

  gemm_qkv_8ph<<<dim3(192), dim3(512), 0, stream>>>(
      hsb, Wqb, bq, bk, bv, Qw, Kw, Vw, QSCL);

  attn_causal<<<dim3(512), dim3(512), 0, stream>>>(Qw, Kw, Vw, AO);

  gemm_bt_bias<float><<<dim3(H_ / 128, M / 128), dim3(256), 0, stream>>>(
      AO, Wob, bo, out, M, H_, H_);
}